// Round 2
// baseline (3608.355 us; speedup 1.0000x reference)
//
#include <hip/hip_runtime.h>
#include <hip/hip_bf16.h>
#include <math.h>

#define EE 512      // E
#define HH 1024     // H
#define VV 50257    // V
#define KVN 1000    // KV
#define BB 64       // B
#define LL 512      // L
#define FH 4096     // 4H
#define TWOH 2048   // 2H

typedef __hip_bfloat16 bf16;

__device__ __forceinline__ float sigm(float x){ return 1.0f/(1.0f+__expf(-x)); }

// ---------------- gates = emb[ids] @ W_ih + h @ W_hh + b_ih + b_hh ----------------
// grid (FH/256, BB/8), block 256. LDS stages 8 rows of cat(x,h) (48 KB).
__global__ __launch_bounds__(256)
void k_embed_gates(const int* __restrict__ ids, const float* __restrict__ h,
                   const float* __restrict__ emb,
                   const float* __restrict__ W_ih, const float* __restrict__ W_hh,
                   const float* __restrict__ b_ih, const float* __restrict__ b_hh,
                   float* __restrict__ gates){
  __shared__ float xh[8][1536];
  const int j  = blockIdx.x*256 + threadIdx.x;
  const int b0 = blockIdx.y*8;
  for (int t = threadIdx.x; t < 8*1536; t += 256){
    int bb = t / 1536, kk = t - bb*1536;
    int b = b0 + bb;
    float v;
    if (kk < EE) v = emb[(size_t)ids[b]*EE + kk];
    else         v = h[(size_t)b*HH + (kk-EE)];
    xh[bb][kk] = v;
  }
  __syncthreads();
  float acc[8];
  #pragma unroll
  for (int i=0;i<8;i++) acc[i]=0.f;
  for (int k=0;k<1536;k++){
    float w = (k<EE) ? W_ih[(size_t)k*FH + j] : W_hh[(size_t)(k-EE)*FH + j];
    #pragma unroll
    for (int i=0;i<8;i++) acc[i] += xh[i][k]*w;
  }
  const float bias = b_ih[j] + b_hh[j];
  #pragma unroll
  for (int i=0;i<8;i++) gates[(size_t)(b0+i)*FH + j] = acc[i] + bias;
}

// ---------------- LSTM cell elementwise ----------------
__global__ __launch_bounds__(256)
void k_lstm(const float* __restrict__ gates, const float* __restrict__ c_in,
            float* __restrict__ hout, float* __restrict__ cout){
  int idx = blockIdx.x*256 + threadIdx.x;      // b*H + hh
  int b = idx >> 10, hh = idx & 1023;
  const float* g = gates + (size_t)b*FH;
  float ig = g[hh], fg = g[HH+hh], gg = g[2*HH+hh], og = g[3*HH+hh];
  float ct = sigm(fg)*c_in[idx] + sigm(ig)*tanhf(gg);
  float ht = sigm(og)*tanhf(ct);
  hout[idx] = ht;
  cout[idx] = ct;
}

// ---------------- q1 = h_t@aW1[H:2H] + ab1 ; p1 = ctx@kW1[:H] + h_t@kW1[H:2H] + kb1 ----------------
// grid (E/256, BB)
__global__ __launch_bounds__(256)
void k_q1p1(const float* __restrict__ ht, const float* __restrict__ ctx,
            const float* __restrict__ aW1, const float* __restrict__ ab1,
            const float* __restrict__ kW1, const float* __restrict__ kb1,
            float* __restrict__ q1, float* __restrict__ p1){
  int e = blockIdx.x*256 + threadIdx.x;
  int b = blockIdx.y;
  float aq = 0.f, ap = 0.f;
  for (int k2 = 0; k2 < HH; ++k2){
    float hv = ht[(size_t)b*HH + k2];
    float cv = ctx[(size_t)b*HH + k2];
    aq += hv * aW1[(size_t)(HH+k2)*EE + e];
    ap += cv * kW1[(size_t)k2*EE + e];
    ap += hv * kW1[(size_t)(HH+k2)*EE + e];
  }
  q1[(size_t)b*EE + e] = aq + ab1[e];
  p1[(size_t)b*EE + e] = ap + kb1[e];
}

// ---------------- p2[kv,e] = k[kv] @ kW1[2H:,:] ----------------
// grid (E/256, KVN)
__global__ __launch_bounds__(256)
void k_p2(const float* __restrict__ kin, const float* __restrict__ kW1,
          float* __restrict__ p2){
  int e  = blockIdx.x*256 + threadIdx.x;
  int kv = blockIdx.y;
  float a = 0.f;
  for (int k2 = 0; k2 < EE; ++k2)
    a += kin[(size_t)kv*EE + k2] * kW1[(size_t)(TWOH+k2)*EE + e];
  p2[(size_t)kv*EE + e] = a;
}

// ---------------- UK1[b,kv,e] = bf16(tanh(p1[b,e] + p2[kv,e])) ----------------
__global__ __launch_bounds__(256)
void k_uk1(const float* __restrict__ p1, const float* __restrict__ p2,
           bf16* __restrict__ uk1){
  int idx = blockIdx.x*256 + threadIdx.x;           // < BB*KVN*EE = 32,768,000
  int e   = idx & (EE-1);
  int r   = idx >> 9;                                // b*KVN + kv
  int b   = r / KVN;
  int kv  = r - b*KVN;
  float v = tanhf(p1[(size_t)b*EE + e] + p2[(size_t)kv*EE + e]);
  uk1[idx] = __float2bfloat16(v);
}

// ---------------- U1[m,n] = bf16(tanh(enc[m,:1024]@aW1[:1024] + q1[b,n])) ----------------
// grid (EE/64, M/64) block 256, 64x64 tile, Kstep 16, K=1024
__global__ __launch_bounds__(256)
void k_gemm_a1(const float* __restrict__ enc, const float* __restrict__ aW1,
               const float* __restrict__ q1, bf16* __restrict__ U1){
  __shared__ float As[16][68];
  __shared__ float Bs[16][64];
  const int tid = threadIdx.x;
  const int tx = tid & 15, ty = tid >> 4;
  const int n0 = blockIdx.x*64, m0 = blockIdx.y*64;
  float acc[4][4] = {};
  for (int k0 = 0; k0 < HH; k0 += 16){
    #pragma unroll
    for (int i=0;i<4;i++){
      int t = tid + i*256;
      int kk = t & 15, mm = t >> 4;
      As[kk][mm] = enc[(size_t)(m0+mm)*HH + k0 + kk];
    }
    #pragma unroll
    for (int i=0;i<4;i++){
      int t = tid + i*256;
      int nn = t & 63, kk = t >> 6;
      Bs[kk][nn] = aW1[(size_t)(k0+kk)*EE + n0 + nn];
    }
    __syncthreads();
    #pragma unroll
    for (int kk=0;kk<16;kk++){
      float a0[4], b0[4];
      #pragma unroll
      for (int i=0;i<4;i++) a0[i] = As[kk][ty*4+i];
      #pragma unroll
      for (int j=0;j<4;j++) b0[j] = Bs[kk][tx*4+j];
      #pragma unroll
      for (int i=0;i<4;i++)
        #pragma unroll
        for (int j=0;j<4;j++)
          acc[i][j] += a0[i]*b0[j];
    }
    __syncthreads();
  }
  #pragma unroll
  for (int i=0;i<4;i++){
    int m = m0 + ty*4 + i;
    int b = m >> 9;                       // m / L
    #pragma unroll
    for (int j=0;j<4;j++){
      int n = n0 + tx*4 + j;
      float v = tanhf(acc[i][j] + q1[(size_t)b*EE + n]);
      U1[(size_t)m*EE + n] = __float2bfloat16(v);
    }
  }
}

// ---------------- logits[m] += sum_n tanh((A@W)[m,n] + bias[n]) * w3[n] ----------------
// A bf16 [M,512], W f32 [512,512]. grid (EE/64, M/64) block 256.
__global__ __launch_bounds__(256)
void k_gemm_tanh_dot(const bf16* __restrict__ A, const float* __restrict__ W,
                     const float* __restrict__ bias, const float* __restrict__ w3,
                     float* __restrict__ logits){
  __shared__ float As[16][68];
  __shared__ float Bs[16][64];
  __shared__ float red[64][17];
  const int tid = threadIdx.x;
  const int tx = tid & 15, ty = tid >> 4;
  const int n0 = blockIdx.x*64, m0 = blockIdx.y*64;
  float acc[4][4] = {};
  for (int k0 = 0; k0 < EE; k0 += 16){
    #pragma unroll
    for (int i=0;i<4;i++){
      int t = tid + i*256;
      int kk = t & 15, mm = t >> 4;
      As[kk][mm] = __bfloat162float(A[(size_t)(m0+mm)*EE + k0 + kk]);
    }
    #pragma unroll
    for (int i=0;i<4;i++){
      int t = tid + i*256;
      int nn = t & 63, kk = t >> 6;
      Bs[kk][nn] = W[(size_t)(k0+kk)*EE + n0 + nn];
    }
    __syncthreads();
    #pragma unroll
    for (int kk=0;kk<16;kk++){
      float a0[4], b0[4];
      #pragma unroll
      for (int i=0;i<4;i++) a0[i] = As[kk][ty*4+i];
      #pragma unroll
      for (int j=0;j<4;j++) b0[j] = Bs[kk][tx*4+j];
      #pragma unroll
      for (int i=0;i<4;i++)
        #pragma unroll
        for (int j=0;j<4;j++)
          acc[i][j] += a0[i]*b0[j];
    }
    __syncthreads();
  }
  float rp[4];
  #pragma unroll
  for (int i=0;i<4;i++){
    float s = 0.f;
    #pragma unroll
    for (int j=0;j<4;j++){
      int n = n0 + tx*4 + j;
      s += tanhf(acc[i][j] + bias[n]) * w3[n];
    }
    rp[i] = s;
  }
  #pragma unroll
  for (int i=0;i<4;i++) red[ty*4+i][tx] = rp[i];
  __syncthreads();
  if (tid < 64){
    float s = 0.f;
    #pragma unroll
    for (int t=0;t<16;t++) s += red[tid][t];
    atomicAdd(&logits[m0 + tid], s);
  }
}

// ---------------- init attention/key logits to their scalar biases ----------------
__global__ __launch_bounds__(256)
void k_init_logits(float* __restrict__ ulog, float* __restrict__ uklog,
                   const float* __restrict__ ab3, const float* __restrict__ kb3){
  int i = blockIdx.x*256 + threadIdx.x;           // grid covers 64000
  if (i < BB*LL)  ulog[i]  = ab3[0];
  if (i < BB*KVN) uklog[i] = kb3[0];
}

// ---------------- softmax over L=512, in place. grid BB, block 256 ----------------
__global__ __launch_bounds__(256)
void k_softmax(float* __restrict__ ulog){
  __shared__ float sdata[256];
  int b = blockIdx.x, tid = threadIdx.x;
  float* row = ulog + (size_t)b*LL;
  float v0 = row[tid], v1 = row[tid+256];
  sdata[tid] = fmaxf(v0, v1);
  __syncthreads();
  for (int s=128;s>0;s>>=1){ if (tid<s) sdata[tid]=fmaxf(sdata[tid],sdata[tid+s]); __syncthreads(); }
  float mx = sdata[0];
  __syncthreads();
  float e0 = __expf(v0-mx), e1 = __expf(v1-mx);
  sdata[tid] = e0+e1;
  __syncthreads();
  for (int s=128;s>0;s>>=1){ if (tid<s) sdata[tid]+=sdata[tid+s]; __syncthreads(); }
  float inv = 1.f/sdata[0];
  row[tid]     = e0*inv;
  row[tid+256] = e1*inv;
}

// ---------------- h_ctx[b,h] = sum_l a[b,l]*enc[b,l,h]. grid (H/256, BB) ----------------
__global__ __launch_bounds__(256)
void k_hctx(const float* __restrict__ a, const float* __restrict__ enc,
            float* __restrict__ hctx){
  int hh = blockIdx.x*256 + threadIdx.x;
  int b  = blockIdx.y;
  float s = 0.f;
  for (int l=0;l<LL;l++)
    s += a[(size_t)b*LL + l] * enc[((size_t)b*LL + l)*HH + hh];
  hctx[(size_t)b*HH + hh] = s;
}

// ---------------- hcatT[k][b]: transpose of cat(h_t, h_ctx). grid 512 ----------------
__global__ __launch_bounds__(256)
void k_hcatT(const float* __restrict__ ht, const float* __restrict__ hctx,
             float* __restrict__ hcatT){
  int idx = blockIdx.x*256 + threadIdx.x;        // < 2048*64
  int b = idx & 63, kk = idx >> 6;
  float v = (kk < HH) ? ht[(size_t)b*HH + kk] : hctx[(size_t)b*HH + (kk-HH)];
  hcatT[idx] = v;
}

// ---------------- o_t[b,v] = hcat[b]@alW[:,v] + alb[v] + vk. grid ceil(V/256) ----------------
__global__ __launch_bounds__(256)
void k_final(const float* __restrict__ hcatT, const float* __restrict__ alW,
             const float* __restrict__ alb, const float* __restrict__ uklog,
             float* __restrict__ y){
  int v = blockIdx.x*256 + threadIdx.x;
  bool ok = v < VV;
  float acc[64];
  #pragma unroll
  for (int i=0;i<64;i++) acc[i]=0.f;
  for (int k0=0;k0<TWOH;k0+=8){
    float w8[8];
    #pragma unroll
    for (int u=0;u<8;u++) w8[u] = ok ? alW[(size_t)(k0+u)*VV + v] : 0.f;
    #pragma unroll
    for (int u=0;u<8;u++){
      const float* hp = hcatT + (size_t)(k0+u)*64;
      #pragma unroll
      for (int b=0;b<64;b++) acc[b] += hp[b]*w8[u];
    }
  }
  if (ok){
    float bias = alb[v];
    int dk = v - (VV - KVN);
    #pragma unroll
    for (int b=0;b<64;b++){
      float o = acc[b] + bias;
      if (dk >= 0) o += uklog[b*KVN + dk];
      y[(size_t)b*VV + v] = o;
    }
  }
}

// ---------------- in-place log_softmax over V per row. grid BB ----------------
__global__ __launch_bounds__(256)
void k_logsoftmax(float* __restrict__ y){
  __shared__ float sdata[256];
  int b = blockIdx.x, tid = threadIdx.x;
  float* row = y + (size_t)b*VV;
  float m = -1e30f;
  for (int i=tid;i<VV;i+=256) m = fmaxf(m, row[i]);
  sdata[tid] = m; __syncthreads();
  for (int s=128;s>0;s>>=1){ if (tid<s) sdata[tid]=fmaxf(sdata[tid],sdata[tid+s]); __syncthreads(); }
  float mx = sdata[0]; __syncthreads();
  float sum = 0.f;
  for (int i=tid;i<VV;i+=256) sum += __expf(row[i]-mx);
  sdata[tid] = sum; __syncthreads();
  for (int s=128;s>0;s>>=1){ if (tid<s) sdata[tid]+=sdata[tid+s]; __syncthreads(); }
  float lse = mx + logf(sdata[0]);
  for (int i=tid;i<VV;i+=256) row[i] -= lse;
}

extern "C" void kernel_launch(void* const* d_in, const int* in_sizes, int n_in,
                              void* d_out, int out_size, void* d_ws, size_t ws_size,
                              hipStream_t stream) {
  const int*   ids  = (const int*)  d_in[0];
  const float* h    = (const float*)d_in[1];
  const float* c    = (const float*)d_in[2];
  const float* kin  = (const float*)d_in[3];
  const float* ctx  = (const float*)d_in[4];
  const float* enc  = (const float*)d_in[5];
  const float* emb  = (const float*)d_in[6];
  const float* W_ih = (const float*)d_in[7];
  const float* W_hh = (const float*)d_in[8];
  const float* b_ih = (const float*)d_in[9];
  const float* b_hh = (const float*)d_in[10];
  const float* aW1  = (const float*)d_in[11];
  const float* ab1  = (const float*)d_in[12];
  const float* aW2  = (const float*)d_in[13];
  const float* ab2  = (const float*)d_in[14];
  const float* aW3  = (const float*)d_in[15];
  const float* ab3  = (const float*)d_in[16];
  const float* kW1  = (const float*)d_in[17];
  const float* kb1  = (const float*)d_in[18];
  const float* kW2  = (const float*)d_in[19];
  const float* kb2  = (const float*)d_in[20];
  const float* kW3  = (const float*)d_in[21];
  const float* kb3  = (const float*)d_in[22];
  const float* alW  = (const float*)d_in[23];
  const float* alb  = (const float*)d_in[24];

  float* y      = (float*)d_out;
  float* ht_out = y + (size_t)BB*VV;
  float* ct_out = ht_out + (size_t)BB*HH;

  char* w = (char*)d_ws;
  float* gates = (float*)w;  w += (size_t)BB*FH*4;        // 1 MB
  float* q1    = (float*)w;  w += (size_t)BB*EE*4;
  float* p1    = (float*)w;  w += (size_t)BB*EE*4;
  float* p2    = (float*)w;  w += (size_t)KVN*EE*4;       // 2 MB
  float* ulog  = (float*)w;  w += (size_t)BB*LL*4;
  float* uklog = (float*)w;  w += (size_t)BB*KVN*4;
  float* hctx  = (float*)w;  w += (size_t)BB*HH*4;
  float* hcatT = (float*)w;  w += (size_t)TWOH*BB*4;
  bf16*  U1    = (bf16*)w;   w += (size_t)BB*LL*EE*2;     // 33.5 MB
  bf16*  UK1   = (bf16*)w;   w += (size_t)BB*KVN*EE*2;    // 65.5 MB

  // 1. LSTM front-end
  k_embed_gates<<<dim3(FH/256, BB/8), 256, 0, stream>>>(ids, h, emb, W_ih, W_hh, b_ih, b_hh, gates);
  k_lstm<<<(BB*HH)/256, 256, 0, stream>>>(gates, c, ht_out, ct_out);

  // 2. logits init (bias of third MLP layers)
  k_init_logits<<<(BB*KVN)/256 + 1, 256, 0, stream>>>(ulog, uklog, ab3, kb3);

  // 3. small precomputes
  k_q1p1<<<dim3(EE/256, BB), 256, 0, stream>>>(ht_out, ctx, aW1, ab1, kW1, kb1, q1, p1);
  k_p2<<<dim3(EE/256, KVN), 256, 0, stream>>>(kin, kW1, p2);

  // 4. key-attention path (rank-collapsed layer 1, then GEMM2 fused with dot-w3)
  k_uk1<<<(BB*KVN*EE)/256, 256, 0, stream>>>(p1, p2, UK1);
  k_gemm_tanh_dot<<<dim3(EE/64, (BB*KVN)/64), 256, 0, stream>>>(UK1, kW2, kb2, kW3, uklog);

  // 5. additive attention path
  k_gemm_a1<<<dim3(EE/64, (BB*LL)/64), 256, 0, stream>>>(enc, aW1, q1, U1);
  k_gemm_tanh_dot<<<dim3(EE/64, (BB*LL)/64), 256, 0, stream>>>(U1, aW2, ab2, aW3, ulog);
  k_softmax<<<BB, 256, 0, stream>>>(ulog);
  k_hctx<<<dim3(HH/256, BB), 256, 0, stream>>>(ulog, enc, hctx);

  // 6. output projection + log_softmax
  k_hcatT<<<(TWOH*BB)/256, 256, 0, stream>>>(ht_out, hctx, hcatT);
  k_final<<<(VV + 255)/256, 256, 0, stream>>>(hcatT, alW, alb, uklog, y);
  k_logsoftmax<<<BB, 256, 0, stream>>>(y);
}

// Round 3
// 1731.272 us; speedup vs baseline: 2.0842x; 2.0842x over previous
//
#include <hip/hip_runtime.h>
#include <hip/hip_bf16.h>
#include <math.h>

#define EE 512      // E
#define HH 1024     // H
#define VV 50257    // V
#define KVN 1000    // KV
#define BB 64       // B
#define LL 512      // L
#define FH 4096     // 4H
#define TWOH 2048   // 2H

typedef __hip_bfloat16 bf16;
typedef short bf16x8 __attribute__((ext_vector_type(8)));
typedef float f32x4  __attribute__((ext_vector_type(4)));

__device__ __forceinline__ float sigm(float x){ return 1.0f/(1.0f+__expf(-x)); }

// RNE fp32 -> bf16 bits
__device__ __forceinline__ unsigned short f2bf(float f){
  unsigned int u = __float_as_uint(f);
  unsigned int r = (u + 0x7FFFu + ((u >> 16) & 1u)) >> 16;
  return (unsigned short)r;
}

// ---------------- gates = emb[ids] @ W_ih + h @ W_hh + b_ih + b_hh ----------------
__global__ __launch_bounds__(256)
void k_embed_gates(const int* __restrict__ ids, const float* __restrict__ h,
                   const float* __restrict__ emb,
                   const float* __restrict__ W_ih, const float* __restrict__ W_hh,
                   const float* __restrict__ b_ih, const float* __restrict__ b_hh,
                   float* __restrict__ gates){
  __shared__ float xh[8][1536];
  const int j  = blockIdx.x*256 + threadIdx.x;
  const int b0 = blockIdx.y*8;
  for (int t = threadIdx.x; t < 8*1536; t += 256){
    int bb = t / 1536, kk = t - bb*1536;
    int b = b0 + bb;
    float v;
    if (kk < EE) v = emb[(size_t)ids[b]*EE + kk];
    else         v = h[(size_t)b*HH + (kk-EE)];
    xh[bb][kk] = v;
  }
  __syncthreads();
  float acc[8];
  #pragma unroll
  for (int i=0;i<8;i++) acc[i]=0.f;
  for (int k=0;k<1536;k++){
    float w = (k<EE) ? W_ih[(size_t)k*FH + j] : W_hh[(size_t)(k-EE)*FH + j];
    #pragma unroll
    for (int i=0;i<8;i++) acc[i] += xh[i][k]*w;
  }
  const float bias = b_ih[j] + b_hh[j];
  #pragma unroll
  for (int i=0;i<8;i++) gates[(size_t)(b0+i)*FH + j] = acc[i] + bias;
}

// ---------------- LSTM cell elementwise ----------------
__global__ __launch_bounds__(256)
void k_lstm(const float* __restrict__ gates, const float* __restrict__ c_in,
            float* __restrict__ hout, float* __restrict__ cout){
  int idx = blockIdx.x*256 + threadIdx.x;
  int b = idx >> 10, hh = idx & 1023;
  const float* g = gates + (size_t)b*FH;
  float ig = g[hh], fg = g[HH+hh], gg = g[2*HH+hh], og = g[3*HH+hh];
  float ct = sigm(fg)*c_in[idx] + sigm(ig)*tanhf(gg);
  float ht = sigm(og)*tanhf(ct);
  hout[idx] = ht;
  cout[idx] = ct;
}

// ---------------- q1/p1 rank-collapsed precomputes ----------------
__global__ __launch_bounds__(256)
void k_q1p1(const float* __restrict__ ht, const float* __restrict__ ctx,
            const float* __restrict__ aW1, const float* __restrict__ ab1,
            const float* __restrict__ kW1, const float* __restrict__ kb1,
            float* __restrict__ q1, float* __restrict__ p1){
  int e = blockIdx.x*256 + threadIdx.x;
  int b = blockIdx.y;
  float aq = 0.f, ap = 0.f;
  for (int k2 = 0; k2 < HH; ++k2){
    float hv = ht[(size_t)b*HH + k2];
    float cv = ctx[(size_t)b*HH + k2];
    aq += hv * aW1[(size_t)(HH+k2)*EE + e];
    ap += cv * kW1[(size_t)k2*EE + e];
    ap += hv * kW1[(size_t)(HH+k2)*EE + e];
  }
  q1[(size_t)b*EE + e] = aq + ab1[e];
  p1[(size_t)b*EE + e] = ap + kb1[e];
}

// ---------------- p2[kv,e] = k[kv] @ kW1[2H:,:] ----------------
__global__ __launch_bounds__(256)
void k_p2(const float* __restrict__ kin, const float* __restrict__ kW1,
          float* __restrict__ p2){
  int e  = blockIdx.x*256 + threadIdx.x;
  int kv = blockIdx.y;
  float a = 0.f;
  for (int k2 = 0; k2 < EE; ++k2)
    a += kin[(size_t)kv*EE + k2] * kW1[(size_t)(TWOH+k2)*EE + e];
  p2[(size_t)kv*EE + e] = a;
}

// ---------------- UK1[b,kv,e] = bf16(tanh(p1[b,e] + p2[kv,e])) ----------------
__global__ __launch_bounds__(256)
void k_uk1(const float* __restrict__ p1, const float* __restrict__ p2,
           bf16* __restrict__ uk1){
  int idx = blockIdx.x*256 + threadIdx.x;
  int e   = idx & (EE-1);
  int r   = idx >> 9;
  int b   = r / KVN;
  int kv  = r - b*KVN;
  float v = tanhf(p1[(size_t)b*EE + e] + p2[(size_t)kv*EE + e]);
  uk1[idx] = __float2bfloat16(v);
}

// ---------------- transpose+convert: Wt[n][k] = bf16(W[k][n]) ----------------
// grid (N/32, K/32), block 256 (32x8)
__global__ __launch_bounds__(256)
void k_transpose_bf16(const float* __restrict__ W, bf16* __restrict__ Wt,
                      int K, int N){
  __shared__ float t[32][33];
  int k0 = blockIdx.y*32, n0 = blockIdx.x*32;
  int tx = threadIdx.x & 31, ty = threadIdx.x >> 5;   // ty 0..7
  #pragma unroll
  for (int i=0;i<4;i++){
    int kk = ty + i*8;
    t[kk][tx] = W[(size_t)(k0+kk)*N + n0 + tx];
  }
  __syncthreads();
  #pragma unroll
  for (int i=0;i<4;i++){
    int nn = ty + i*8;
    Wt[(size_t)(n0+nn)*K + k0 + tx] = __float2bfloat16(t[tx][nn]);
  }
}

// =====================================================================
// MFMA GEMM 1: C = A[M,512]bf16 @ WtT ; logits[m] += sum_n tanh(C+bias[n])*w3[n]
// Wt is bf16 [512][512] = W^T. BM=BN=128, BK=32. block 256 = 4 waves (2x2 of 64x64).
// grid (4, M/128)
// =====================================================================
__global__ __launch_bounds__(256)
void k_mfma_tanh_dot(const bf16* __restrict__ A, const bf16* __restrict__ Wt,
                     const float* __restrict__ bias, const float* __restrict__ w3,
                     float* __restrict__ logits){
  __shared__ short As[128*40];
  __shared__ short Bs[128*40];
  __shared__ float red[128*33];
  const int tid  = threadIdx.x;
  const int lane = tid & 63, wid = tid >> 6;
  const int wm = wid >> 1, wn = wid & 1;
  const int quad = lane >> 4, l16 = lane & 15;
  const int m0 = blockIdx.y*128, n0 = blockIdx.x*128;

  f32x4 acc[4][4] = {};
  for (int k0 = 0; k0 < 512; k0 += 32){
    #pragma unroll
    for (int it = 0; it < 2; ++it){
      int task = tid + it*256;            // 0..511
      int row = task >> 2, cg = task & 3; // 8 bf16 per group
      *(bf16x8*)(As + row*40 + cg*8) =
        *(const bf16x8*)((const short*)A + (size_t)(m0+row)*512 + k0 + cg*8);
      *(bf16x8*)(Bs + row*40 + cg*8) =
        *(const bf16x8*)((const short*)Wt + (size_t)(n0+row)*512 + k0 + cg*8);
    }
    __syncthreads();
    bf16x8 af[4], bfr[4];
    #pragma unroll
    for (int mt=0; mt<4; ++mt)
      af[mt] = *(const bf16x8*)(As + (wm*64 + mt*16 + l16)*40 + quad*8);
    #pragma unroll
    for (int nt=0; nt<4; ++nt)
      bfr[nt] = *(const bf16x8*)(Bs + (wn*64 + nt*16 + l16)*40 + quad*8);
    #pragma unroll
    for (int mt=0; mt<4; ++mt)
      #pragma unroll
      for (int nt=0; nt<4; ++nt)
        acc[mt][nt] = __builtin_amdgcn_mfma_f32_16x16x32_bf16(af[mt], bfr[nt], acc[mt][nt], 0, 0, 0);
    __syncthreads();
  }
  // epilogue: tanh + dot with w3, reduce across n
  float bv[4], wv[4];
  #pragma unroll
  for (int nt=0; nt<4; ++nt){
    int n = n0 + wn*64 + nt*16 + l16;
    bv[nt] = bias[n]; wv[nt] = w3[n];
  }
  #pragma unroll
  for (int mt=0; mt<4; ++mt){
    #pragma unroll
    for (int r=0; r<4; ++r){
      float s = 0.f;
      #pragma unroll
      for (int nt=0; nt<4; ++nt)
        s += tanhf(acc[mt][nt][r] + bv[nt]) * wv[nt];
      int rowL = wm*64 + mt*16 + quad*4 + r;
      red[rowL*33 + wn*16 + l16] = s;
    }
  }
  __syncthreads();
  if (tid < 128){
    float s = 0.f;
    #pragma unroll
    for (int j=0;j<32;j++) s += red[tid*33 + j];
    atomicAdd(&logits[m0 + tid], s);
  }
}

// =====================================================================
// MFMA GEMM 2: U1 = bf16(tanh(enc[M,1024]fp32 @ aW1tT + q1[b,:]))
// enc converted fp32->bf16 during staging. grid (4, 256). K=1024.
// =====================================================================
__global__ __launch_bounds__(256)
void k_mfma_a1(const float* __restrict__ enc, const bf16* __restrict__ Wt,
               const float* __restrict__ q1, bf16* __restrict__ U1){
  __shared__ short As[128*40];
  __shared__ short Bs[128*40];
  const int tid  = threadIdx.x;
  const int lane = tid & 63, wid = tid >> 6;
  const int wm = wid >> 1, wn = wid & 1;
  const int quad = lane >> 4, l16 = lane & 15;
  const int m0 = blockIdx.y*128, n0 = blockIdx.x*128;

  f32x4 acc[4][4] = {};
  for (int k0 = 0; k0 < 1024; k0 += 32){
    // A: fp32 -> bf16 on the fly (1024 float4 tasks)
    #pragma unroll
    for (int it = 0; it < 4; ++it){
      int task = tid + it*256;            // 0..1023
      int row = task >> 3, g = task & 7;  // g: 4 floats each
      float4 f = *(const float4*)(enc + (size_t)(m0+row)*1024 + k0 + g*4);
      uint2 pk;
      pk.x = (unsigned int)f2bf(f.x) | ((unsigned int)f2bf(f.y) << 16);
      pk.y = (unsigned int)f2bf(f.z) | ((unsigned int)f2bf(f.w) << 16);
      *(uint2*)(As + row*40 + g*4) = pk;
    }
    // B: bf16 copy (512 tasks)
    #pragma unroll
    for (int it = 0; it < 2; ++it){
      int task = tid + it*256;
      int row = task >> 2, cg = task & 3;
      *(bf16x8*)(Bs + row*40 + cg*8) =
        *(const bf16x8*)((const short*)Wt + (size_t)(n0+row)*1024 + k0 + cg*8);
    }
    __syncthreads();
    bf16x8 af[4], bfr[4];
    #pragma unroll
    for (int mt=0; mt<4; ++mt)
      af[mt] = *(const bf16x8*)(As + (wm*64 + mt*16 + l16)*40 + quad*8);
    #pragma unroll
    for (int nt=0; nt<4; ++nt)
      bfr[nt] = *(const bf16x8*)(Bs + (wn*64 + nt*16 + l16)*40 + quad*8);
    #pragma unroll
    for (int mt=0; mt<4; ++mt)
      #pragma unroll
      for (int nt=0; nt<4; ++nt)
        acc[mt][nt] = __builtin_amdgcn_mfma_f32_16x16x32_bf16(af[mt], bfr[nt], acc[mt][nt], 0, 0, 0);
    __syncthreads();
  }
  // epilogue: + q1[b,n], tanh, store bf16
  const int b = m0 >> 9;                  // 512 rows per batch; BM=128 divides 512
  const float* q1r = q1 + (size_t)b*EE;
  #pragma unroll
  for (int mt=0; mt<4; ++mt){
    #pragma unroll
    for (int r=0; r<4; ++r){
      int m = m0 + wm*64 + mt*16 + quad*4 + r;
      #pragma unroll
      for (int nt=0; nt<4; ++nt){
        int n = n0 + wn*64 + nt*16 + l16;
        U1[(size_t)m*EE + n] = __float2bfloat16(tanhf(acc[mt][nt][r] + q1r[n]));
      }
    }
  }
}

// ---------------- init attention/key logits to their scalar biases ----------------
__global__ __launch_bounds__(256)
void k_init_logits(float* __restrict__ ulog, float* __restrict__ uklog,
                   const float* __restrict__ ab3, const float* __restrict__ kb3){
  int i = blockIdx.x*256 + threadIdx.x;
  if (i < BB*LL)  ulog[i]  = ab3[0];
  if (i < BB*KVN) uklog[i] = kb3[0];
}

// ---------------- softmax over L=512, in place ----------------
__global__ __launch_bounds__(256)
void k_softmax(float* __restrict__ ulog){
  __shared__ float sdata[256];
  int b = blockIdx.x, tid = threadIdx.x;
  float* row = ulog + (size_t)b*LL;
  float v0 = row[tid], v1 = row[tid+256];
  sdata[tid] = fmaxf(v0, v1);
  __syncthreads();
  for (int s=128;s>0;s>>=1){ if (tid<s) sdata[tid]=fmaxf(sdata[tid],sdata[tid+s]); __syncthreads(); }
  float mx = sdata[0];
  __syncthreads();
  float e0 = __expf(v0-mx), e1 = __expf(v1-mx);
  sdata[tid] = e0+e1;
  __syncthreads();
  for (int s=128;s>0;s>>=1){ if (tid<s) sdata[tid]+=sdata[tid+s]; __syncthreads(); }
  float inv = 1.f/sdata[0];
  row[tid]     = e0*inv;
  row[tid+256] = e1*inv;
}

// ---------------- h_ctx[b,h] = sum_l a[b,l]*enc[b,l,h] ----------------
__global__ __launch_bounds__(256)
void k_hctx(const float* __restrict__ a, const float* __restrict__ enc,
            float* __restrict__ hctx){
  int hh = blockIdx.x*256 + threadIdx.x;
  int b  = blockIdx.y;
  float s = 0.f;
  for (int l=0;l<LL;l++)
    s += a[(size_t)b*LL + l] * enc[((size_t)b*LL + l)*HH + hh];
  hctx[(size_t)b*HH + hh] = s;
}

// ---------------- hcatT[k][b] = transpose of cat(h_t, h_ctx) ----------------
__global__ __launch_bounds__(256)
void k_hcatT(const float* __restrict__ ht, const float* __restrict__ hctx,
             float* __restrict__ hcatT){
  int idx = blockIdx.x*256 + threadIdx.x;
  int b = idx & 63, kk = idx >> 6;
  float v = (kk < HH) ? ht[(size_t)b*HH + kk] : hctx[(size_t)b*HH + (kk-HH)];
  hcatT[idx] = v;
}

// ---------------- y[b][v] = hcat[b]@alW[:,v] + alb[v] + vk ----------------
// 64x64 tile GEMM: M=64(all b), N=64/block, K=2048. block 256, 4x4/thread.
// grid ceil(V/64)=786
__global__ __launch_bounds__(256)
void k_final(const float* __restrict__ hcatT, const float* __restrict__ alW,
             const float* __restrict__ alb, const float* __restrict__ uklog,
             float* __restrict__ y){
  __shared__ float Hs[16][64];   // [k][b]
  __shared__ float Ws[16][64];   // [k][v]
  const int tid = threadIdx.x;
  const int tx = tid & 15, ty = tid >> 4;     // tx -> v-sub, ty -> b-sub
  const int n0 = blockIdx.x * 64;
  float acc[4][4] = {};
  for (int k0 = 0; k0 < TWOH; k0 += 16){
    #pragma unroll
    for (int i=0;i<4;i++){
      int t = tid + i*256;                    // 0..1023
      int kk = t >> 6, cc = t & 63;
      Hs[kk][cc] = hcatT[(size_t)(k0+kk)*64 + cc];
      int v = n0 + cc;
      Ws[kk][cc] = (v < VV) ? alW[(size_t)(k0+kk)*VV + v] : 0.f;
    }
    __syncthreads();
    #pragma unroll
    for (int kk=0;kk<16;kk++){
      float4 hb = *(const float4*)(&Hs[kk][ty*4]);
      float4 wv = *(const float4*)(&Ws[kk][tx*4]);
      float ha[4] = {hb.x, hb.y, hb.z, hb.w};
      float wa[4] = {wv.x, wv.y, wv.z, wv.w};
      #pragma unroll
      for (int i=0;i<4;i++)
        #pragma unroll
        for (int j=0;j<4;j++)
          acc[i][j] += ha[i]*wa[j];
    }
    __syncthreads();
  }
  #pragma unroll
  for (int j=0;j<4;j++){
    int v = n0 + tx*4 + j;
    if (v < VV){
      float bias = alb[v];
      int dk = v - (VV - KVN);
      #pragma unroll
      for (int i=0;i<4;i++){
        int b = ty*4 + i;
        float o = acc[i][j] + bias;
        if (dk >= 0) o += uklog[b*KVN + dk];
        y[(size_t)b*VV + v] = o;
      }
    }
  }
}

// ---------------- in-place log_softmax over V per row ----------------
__global__ __launch_bounds__(256)
void k_logsoftmax(float* __restrict__ y){
  __shared__ float sdata[256];
  int b = blockIdx.x, tid = threadIdx.x;
  float* row = y + (size_t)b*VV;
  float m = -1e30f;
  for (int i=tid;i<VV;i+=256) m = fmaxf(m, row[i]);
  sdata[tid] = m; __syncthreads();
  for (int s=128;s>0;s>>=1){ if (tid<s) sdata[tid]=fmaxf(sdata[tid],sdata[tid+s]); __syncthreads(); }
  float mx = sdata[0]; __syncthreads();
  float sum = 0.f;
  for (int i=tid;i<VV;i+=256) sum += __expf(row[i]-mx);
  sdata[tid] = sum; __syncthreads();
  for (int s=128;s>0;s>>=1){ if (tid<s) sdata[tid]+=sdata[tid+s]; __syncthreads(); }
  float lse = mx + logf(sdata[0]);
  for (int i=tid;i<VV;i+=256) row[i] -= lse;
}

extern "C" void kernel_launch(void* const* d_in, const int* in_sizes, int n_in,
                              void* d_out, int out_size, void* d_ws, size_t ws_size,
                              hipStream_t stream) {
  const int*   ids  = (const int*)  d_in[0];
  const float* h    = (const float*)d_in[1];
  const float* c    = (const float*)d_in[2];
  const float* kin  = (const float*)d_in[3];
  const float* ctx  = (const float*)d_in[4];
  const float* enc  = (const float*)d_in[5];
  const float* emb  = (const float*)d_in[6];
  const float* W_ih = (const float*)d_in[7];
  const float* W_hh = (const float*)d_in[8];
  const float* b_ih = (const float*)d_in[9];
  const float* b_hh = (const float*)d_in[10];
  const float* aW1  = (const float*)d_in[11];
  const float* ab1  = (const float*)d_in[12];
  const float* aW2  = (const float*)d_in[13];
  const float* ab2  = (const float*)d_in[14];
  const float* aW3  = (const float*)d_in[15];
  const float* ab3  = (const float*)d_in[16];
  const float* kW1  = (const float*)d_in[17];
  const float* kb1  = (const float*)d_in[18];
  const float* kW2  = (const float*)d_in[19];
  const float* kb2  = (const float*)d_in[20];
  const float* kW3  = (const float*)d_in[21];
  const float* kb3  = (const float*)d_in[22];
  const float* alW  = (const float*)d_in[23];
  const float* alb  = (const float*)d_in[24];

  float* y      = (float*)d_out;
  float* ht_out = y + (size_t)BB*VV;
  float* ct_out = ht_out + (size_t)BB*HH;

  char* w = (char*)d_ws;
  float* gates = (float*)w;  w += (size_t)BB*FH*4;        // 1 MB
  float* q1    = (float*)w;  w += (size_t)BB*EE*4;
  float* p1    = (float*)w;  w += (size_t)BB*EE*4;
  float* p2    = (float*)w;  w += (size_t)KVN*EE*4;       // 2 MB
  float* ulog  = (float*)w;  w += (size_t)BB*LL*4;
  float* uklog = (float*)w;  w += (size_t)BB*KVN*4;
  float* hctx  = (float*)w;  w += (size_t)BB*HH*4;
  float* hcatT = (float*)w;  w += (size_t)TWOH*BB*4;
  bf16*  U1    = (bf16*)w;   w += (size_t)BB*LL*EE*2;     // 33.5 MB
  bf16*  UK1   = (bf16*)w;   w += (size_t)BB*KVN*EE*2;    // 65.5 MB
  bf16*  aW1t  = (bf16*)w;   w += (size_t)EE*HH*2;        // 1 MB   [512][1024]
  bf16*  aW2t  = (bf16*)w;   w += (size_t)EE*EE*2;        // 0.5 MB [512][512]
  bf16*  kW2t  = (bf16*)w;   w += (size_t)EE*EE*2;        // 0.5 MB [512][512]

  // 0. weight transposes -> bf16 (independent of everything else)
  k_transpose_bf16<<<dim3(EE/32, HH/32), 256, 0, stream>>>(aW1, aW1t, HH, EE);
  k_transpose_bf16<<<dim3(EE/32, EE/32), 256, 0, stream>>>(aW2, aW2t, EE, EE);
  k_transpose_bf16<<<dim3(EE/32, EE/32), 256, 0, stream>>>(kW2, kW2t, EE, EE);

  // 1. LSTM front-end
  k_embed_gates<<<dim3(FH/256, BB/8), 256, 0, stream>>>(ids, h, emb, W_ih, W_hh, b_ih, b_hh, gates);
  k_lstm<<<(BB*HH)/256, 256, 0, stream>>>(gates, c, ht_out, ct_out);

  // 2. logits init (bias of third MLP layers)
  k_init_logits<<<(BB*KVN)/256 + 1, 256, 0, stream>>>(ulog, uklog, ab3, kb3);

  // 3. small precomputes
  k_q1p1<<<dim3(EE/256, BB), 256, 0, stream>>>(ht_out, ctx, aW1, ab1, kW1, kb1, q1, p1);
  k_p2<<<dim3(EE/256, KVN), 256, 0, stream>>>(kin, kW1, p2);

  // 4. key-attention path: rank-collapsed layer1, then MFMA GEMM2 fused with tanh-dot
  k_uk1<<<(BB*KVN*EE)/256, 256, 0, stream>>>(p1, p2, UK1);
  k_mfma_tanh_dot<<<dim3(4, (BB*KVN)/128), 256, 0, stream>>>(UK1, kW2t, kb2, kW3, uklog);

  // 5. additive attention path (MFMA)
  k_mfma_a1<<<dim3(4, (BB*LL)/128), 256, 0, stream>>>(enc, aW1t, q1, U1);
  k_mfma_tanh_dot<<<dim3(4, (BB*LL)/128), 256, 0, stream>>>(U1, aW2t, ab2, aW3, ulog);
  k_softmax<<<BB, 256, 0, stream>>>(ulog);
  k_hctx<<<dim3(HH/256, BB), 256, 0, stream>>>(ulog, enc, hctx);

  // 6. output projection + log_softmax
  k_hcatT<<<(TWOH*BB)/256, 256, 0, stream>>>(ht_out, hctx, hcatT);
  k_final<<<(VV + 63)/64, 256, 0, stream>>>(hcatT, alW, alb, uklog, y);
  k_logsoftmax<<<BB, 256, 0, stream>>>(y);
}

// Round 4
// 1458.442 us; speedup vs baseline: 2.4741x; 1.1871x over previous
//
#include <hip/hip_runtime.h>
#include <hip/hip_bf16.h>
#include <math.h>

#define EE 512      // E
#define HH 1024     // H
#define VV 50257    // V
#define KVN 1000    // KV
#define BB 64       // B
#define LL 512      // L
#define FH 4096     // 4H
#define TWOH 2048   // 2H

typedef __hip_bfloat16 bf16;
typedef short bf16x8 __attribute__((ext_vector_type(8)));
typedef float f32x4  __attribute__((ext_vector_type(4)));

__device__ __forceinline__ float sigm(float x){ return 1.0f/(1.0f+__expf(-x)); }

// RNE fp32 -> bf16 bits
__device__ __forceinline__ unsigned short f2bf(float f){
  unsigned int u = __float_as_uint(f);
  unsigned int r = (u + 0x7FFFu + ((u >> 16) & 1u)) >> 16;
  return (unsigned short)r;
}

// ---------------- gates init: gates[b][j] = b_ih[j] + b_hh[j] ----------------
__global__ __launch_bounds__(256)
void k_gates_init(const float* __restrict__ b_ih, const float* __restrict__ b_hh,
                  float* __restrict__ gates){
  int i = blockIdx.x*256 + threadIdx.x;     // < 64*4096
  int j = i & (FH-1);
  gates[i] = b_ih[j] + b_hh[j];
}

// ---------------- embed+gates GEMM: gates += cat(emb[ids],h) @ cat(W_ih;W_hh) ----------------
// M=64 (all b), BN=64, BK=64, K-split 24. grid (4096/64, 1536/64) = (64,24), block 256.
// atomicAdd into pre-biased gates.
__global__ __launch_bounds__(256)
void k_embed_gates(const int* __restrict__ ids, const float* __restrict__ h,
                   const float* __restrict__ emb,
                   const float* __restrict__ W_ih, const float* __restrict__ W_hh,
                   float* __restrict__ gates){
  __shared__ float Xs[64][68];   // [k][b]
  __shared__ float Ws[64][68];   // [k][n]
  const int tid = threadIdx.x;
  const int nbase = blockIdx.x*64;
  const int kbase = blockIdx.y*64;
  // stage X transposed: thread t covers b = t>>2, k = (t&3)*16 + i
  {
    int b = tid >> 2;
    int kof = (tid & 3)*16;
    int id = ids[b];
    #pragma unroll
    for (int i=0;i<16;i++){
      int kg = kbase + kof + i;
      float v = (kg < EE) ? emb[(size_t)id*EE + kg] : h[(size_t)b*HH + (kg-EE)];
      Xs[kof+i][b] = v;
    }
  }
  // stage W: thread t covers n = t&63, krow = (t>>6) + i*4
  {
    int n = tid & 63;
    int kr0 = tid >> 6;
    #pragma unroll
    for (int i=0;i<16;i++){
      int kr = kr0 + i*4;
      int kg = kbase + kr;
      float v = (kg < EE) ? W_ih[(size_t)kg*FH + nbase + n]
                          : W_hh[(size_t)(kg-EE)*FH + nbase + n];
      Ws[kr][n] = v;
    }
  }
  __syncthreads();
  const int tx = tid & 15, ty = tid >> 4;
  float acc[4][4] = {};
  for (int k=0;k<64;k++){
    float4 a4 = *(const float4*)(&Xs[k][ty*4]);
    float4 w4 = *(const float4*)(&Ws[k][tx*4]);
    float aa[4] = {a4.x,a4.y,a4.z,a4.w};
    float ww[4] = {w4.x,w4.y,w4.z,w4.w};
    #pragma unroll
    for (int i=0;i<4;i++)
      #pragma unroll
      for (int j=0;j<4;j++)
        acc[i][j] += aa[i]*ww[j];
  }
  #pragma unroll
  for (int i=0;i<4;i++){
    int b = ty*4 + i;
    #pragma unroll
    for (int j=0;j<4;j++)
      atomicAdd(&gates[(size_t)b*FH + nbase + tx*4 + j], acc[i][j]);
  }
}

// ---------------- LSTM cell elementwise ----------------
__global__ __launch_bounds__(256)
void k_lstm(const float* __restrict__ gates, const float* __restrict__ c_in,
            float* __restrict__ hout, float* __restrict__ cout){
  int idx = blockIdx.x*256 + threadIdx.x;
  int b = idx >> 10, hh = idx & 1023;
  const float* g = gates + (size_t)b*FH;
  float ig = g[hh], fg = g[HH+hh], gg = g[2*HH+hh], og = g[3*HH+hh];
  float ct = sigm(fg)*c_in[idx] + sigm(ig)*tanhf(gg);
  float ht = sigm(og)*tanhf(ct);
  hout[idx] = ht;
  cout[idx] = ct;
}

// ---------------- q1/p1 rank-collapsed precomputes ----------------
__global__ __launch_bounds__(256)
void k_q1p1(const float* __restrict__ ht, const float* __restrict__ ctx,
            const float* __restrict__ aW1, const float* __restrict__ ab1,
            const float* __restrict__ kW1, const float* __restrict__ kb1,
            float* __restrict__ q1, float* __restrict__ p1){
  int e = blockIdx.x*256 + threadIdx.x;
  int b = blockIdx.y;
  float aq = 0.f, ap = 0.f;
  for (int k2 = 0; k2 < HH; ++k2){
    float hv = ht[(size_t)b*HH + k2];
    float cv = ctx[(size_t)b*HH + k2];
    aq += hv * aW1[(size_t)(HH+k2)*EE + e];
    ap += cv * kW1[(size_t)k2*EE + e];
    ap += hv * kW1[(size_t)(HH+k2)*EE + e];
  }
  q1[(size_t)b*EE + e] = aq + ab1[e];
  p1[(size_t)b*EE + e] = ap + kb1[e];
}

// ---------------- p2[kv,e] = k[kv] @ kW1[2H:,:] ----------------
__global__ __launch_bounds__(256)
void k_p2(const float* __restrict__ kin, const float* __restrict__ kW1,
          float* __restrict__ p2){
  int e  = blockIdx.x*256 + threadIdx.x;
  int kv = blockIdx.y;
  float a = 0.f;
  for (int k2 = 0; k2 < EE; ++k2)
    a += kin[(size_t)kv*EE + k2] * kW1[(size_t)(TWOH+k2)*EE + e];
  p2[(size_t)kv*EE + e] = a;
}

// ---------------- transpose+convert: Wt[n][k] = bf16(W[k][n]) ----------------
__global__ __launch_bounds__(256)
void k_transpose_bf16(const float* __restrict__ W, bf16* __restrict__ Wt,
                      int K, int N){
  __shared__ float t[32][33];
  int k0 = blockIdx.y*32, n0 = blockIdx.x*32;
  int tx = threadIdx.x & 31, ty = threadIdx.x >> 5;
  #pragma unroll
  for (int i=0;i<4;i++){
    int kk = ty + i*8;
    t[kk][tx] = W[(size_t)(k0+kk)*N + n0 + tx];
  }
  __syncthreads();
  #pragma unroll
  for (int i=0;i<4;i++){
    int nn = ty + i*8;
    Wt[(size_t)(n0+nn)*K + k0 + tx] = __float2bfloat16(t[tx][nn]);
  }
}

// =====================================================================
// MFMA GEMM: logits[m] += sum_n tanh((A@Wt^T)[m,n] + bias[n]) * w3[n]
// A bf16 [M,512] materialized. BM=BN=128, BK=32. grid (4, M/128).
// shuffle-reduce epilogue (no red LDS).
// =====================================================================
__global__ __launch_bounds__(256)
void k_mfma_tanh_dot(const bf16* __restrict__ A, const bf16* __restrict__ Wt,
                     const float* __restrict__ bias, const float* __restrict__ w3,
                     float* __restrict__ logits){
  __shared__ short As[128*40];
  __shared__ short Bs[128*40];
  const int tid  = threadIdx.x;
  const int lane = tid & 63, wid = tid >> 6;
  const int wm = wid >> 1, wn = wid & 1;
  const int quad = lane >> 4, l16 = lane & 15;
  const int m0 = blockIdx.y*128, n0 = blockIdx.x*128;

  f32x4 acc[4][4] = {};
  for (int k0 = 0; k0 < 512; k0 += 32){
    #pragma unroll
    for (int it = 0; it < 2; ++it){
      int task = tid + it*256;
      int row = task >> 2, cg = task & 3;
      *(bf16x8*)(As + row*40 + cg*8) =
        *(const bf16x8*)((const short*)A + (size_t)(m0+row)*512 + k0 + cg*8);
      *(bf16x8*)(Bs + row*40 + cg*8) =
        *(const bf16x8*)((const short*)Wt + (size_t)(n0+row)*512 + k0 + cg*8);
    }
    __syncthreads();
    bf16x8 af[4], bfr[4];
    #pragma unroll
    for (int mt=0; mt<4; ++mt)
      af[mt] = *(const bf16x8*)(As + (wm*64 + mt*16 + l16)*40 + quad*8);
    #pragma unroll
    for (int nt=0; nt<4; ++nt)
      bfr[nt] = *(const bf16x8*)(Bs + (wn*64 + nt*16 + l16)*40 + quad*8);
    #pragma unroll
    for (int mt=0; mt<4; ++mt)
      #pragma unroll
      for (int nt=0; nt<4; ++nt)
        acc[mt][nt] = __builtin_amdgcn_mfma_f32_16x16x32_bf16(af[mt], bfr[nt], acc[mt][nt], 0, 0, 0);
    __syncthreads();
  }
  float bv[4], wv[4];
  #pragma unroll
  for (int nt=0; nt<4; ++nt){
    int n = n0 + wn*64 + nt*16 + l16;
    bv[nt] = bias[n]; wv[nt] = w3[n];
  }
  #pragma unroll
  for (int mt=0; mt<4; ++mt){
    #pragma unroll
    for (int r=0; r<4; ++r){
      float s = 0.f;
      #pragma unroll
      for (int nt=0; nt<4; ++nt)
        s += tanhf(acc[mt][nt][r] + bv[nt]) * wv[nt];
      #pragma unroll
      for (int off=8; off>=1; off>>=1) s += __shfl_xor(s, off, 16);
      if (l16 == 0){
        int row = wm*64 + mt*16 + quad*4 + r;
        atomicAdd(&logits[m0 + row], s);
      }
    }
  }
}

// =====================================================================
// Key-path fused: A[m,e] = tanh(p1[b,e]+p2[kv,e]) computed during staging.
// logits[m] += sum_n tanh((A@kW2t^T)[m,n]+kb2[n])*kW3[n].  grid (4, 500).
// =====================================================================
__global__ __launch_bounds__(256)
void k_mfma_key(const float* __restrict__ p1, const float* __restrict__ p2,
                const bf16* __restrict__ Wt,
                const float* __restrict__ bias, const float* __restrict__ w3,
                float* __restrict__ logits){
  __shared__ short As[128*40];
  __shared__ short Bs[128*40];
  const int tid  = threadIdx.x;
  const int lane = tid & 63, wid = tid >> 6;
  const int wm = wid >> 1, wn = wid & 1;
  const int quad = lane >> 4, l16 = lane & 15;
  const int m0 = blockIdx.y*128, n0 = blockIdx.x*128;

  f32x4 acc[4][4] = {};
  for (int k0 = 0; k0 < 512; k0 += 32){
    #pragma unroll
    for (int it = 0; it < 2; ++it){
      int grp = tid + it*256;             // 512 groups of 8
      int row = grp >> 2, cg = grp & 3;
      int r = m0 + row;
      int b = r / KVN;
      int kv = r - b*KVN;
      int e = k0 + cg*8;
      float4 a0 = *(const float4*)(p1 + (size_t)b*EE + e);
      float4 a1 = *(const float4*)(p1 + (size_t)b*EE + e + 4);
      float4 c0 = *(const float4*)(p2 + (size_t)kv*EE + e);
      float4 c1 = *(const float4*)(p2 + (size_t)kv*EE + e + 4);
      bf16x8 v;
      v[0]=(short)f2bf(tanhf(a0.x+c0.x)); v[1]=(short)f2bf(tanhf(a0.y+c0.y));
      v[2]=(short)f2bf(tanhf(a0.z+c0.z)); v[3]=(short)f2bf(tanhf(a0.w+c0.w));
      v[4]=(short)f2bf(tanhf(a1.x+c1.x)); v[5]=(short)f2bf(tanhf(a1.y+c1.y));
      v[6]=(short)f2bf(tanhf(a1.z+c1.z)); v[7]=(short)f2bf(tanhf(a1.w+c1.w));
      *(bf16x8*)(As + row*40 + cg*8) = v;
      *(bf16x8*)(Bs + row*40 + cg*8) =
        *(const bf16x8*)((const short*)Wt + (size_t)(n0+row)*512 + k0 + cg*8);
    }
    __syncthreads();
    bf16x8 af[4], bfr[4];
    #pragma unroll
    for (int mt=0; mt<4; ++mt)
      af[mt] = *(const bf16x8*)(As + (wm*64 + mt*16 + l16)*40 + quad*8);
    #pragma unroll
    for (int nt=0; nt<4; ++nt)
      bfr[nt] = *(const bf16x8*)(Bs + (wn*64 + nt*16 + l16)*40 + quad*8);
    #pragma unroll
    for (int mt=0; mt<4; ++mt)
      #pragma unroll
      for (int nt=0; nt<4; ++nt)
        acc[mt][nt] = __builtin_amdgcn_mfma_f32_16x16x32_bf16(af[mt], bfr[nt], acc[mt][nt], 0, 0, 0);
    __syncthreads();
  }
  float bv[4], wv[4];
  #pragma unroll
  for (int nt=0; nt<4; ++nt){
    int n = n0 + wn*64 + nt*16 + l16;
    bv[nt] = bias[n]; wv[nt] = w3[n];
  }
  #pragma unroll
  for (int mt=0; mt<4; ++mt){
    #pragma unroll
    for (int r=0; r<4; ++r){
      float s = 0.f;
      #pragma unroll
      for (int nt=0; nt<4; ++nt)
        s += tanhf(acc[mt][nt][r] + bv[nt]) * wv[nt];
      #pragma unroll
      for (int off=8; off>=1; off>>=1) s += __shfl_xor(s, off, 16);
      if (l16 == 0){
        int row = wm*64 + mt*16 + quad*4 + r;
        atomicAdd(&logits[m0 + row], s);
      }
    }
  }
}

// =====================================================================
// MFMA GEMM: U1 = bf16(tanh(enc[M,1024]fp32 @ aW1t^T + q1[b,:])). grid (4, 256).
// =====================================================================
__global__ __launch_bounds__(256)
void k_mfma_a1(const float* __restrict__ enc, const bf16* __restrict__ Wt,
               const float* __restrict__ q1, bf16* __restrict__ U1){
  __shared__ short As[128*40];
  __shared__ short Bs[128*40];
  const int tid  = threadIdx.x;
  const int lane = tid & 63, wid = tid >> 6;
  const int wm = wid >> 1, wn = wid & 1;
  const int quad = lane >> 4, l16 = lane & 15;
  const int m0 = blockIdx.y*128, n0 = blockIdx.x*128;

  f32x4 acc[4][4] = {};
  for (int k0 = 0; k0 < 1024; k0 += 32){
    #pragma unroll
    for (int it = 0; it < 4; ++it){
      int task = tid + it*256;
      int row = task >> 3, g = task & 7;
      float4 f = *(const float4*)(enc + (size_t)(m0+row)*1024 + k0 + g*4);
      uint2 pk;
      pk.x = (unsigned int)f2bf(f.x) | ((unsigned int)f2bf(f.y) << 16);
      pk.y = (unsigned int)f2bf(f.z) | ((unsigned int)f2bf(f.w) << 16);
      *(uint2*)(As + row*40 + g*4) = pk;
    }
    #pragma unroll
    for (int it = 0; it < 2; ++it){
      int task = tid + it*256;
      int row = task >> 2, cg = task & 3;
      *(bf16x8*)(Bs + row*40 + cg*8) =
        *(const bf16x8*)((const short*)Wt + (size_t)(n0+row)*1024 + k0 + cg*8);
    }
    __syncthreads();
    bf16x8 af[4], bfr[4];
    #pragma unroll
    for (int mt=0; mt<4; ++mt)
      af[mt] = *(const bf16x8*)(As + (wm*64 + mt*16 + l16)*40 + quad*8);
    #pragma unroll
    for (int nt=0; nt<4; ++nt)
      bfr[nt] = *(const bf16x8*)(Bs + (wn*64 + nt*16 + l16)*40 + quad*8);
    #pragma unroll
    for (int mt=0; mt<4; ++mt)
      #pragma unroll
      for (int nt=0; nt<4; ++nt)
        acc[mt][nt] = __builtin_amdgcn_mfma_f32_16x16x32_bf16(af[mt], bfr[nt], acc[mt][nt], 0, 0, 0);
    __syncthreads();
  }
  const int b = m0 >> 9;
  const float* q1r = q1 + (size_t)b*EE;
  #pragma unroll
  for (int mt=0; mt<4; ++mt){
    #pragma unroll
    for (int r=0; r<4; ++r){
      int m = m0 + wm*64 + mt*16 + quad*4 + r;
      #pragma unroll
      for (int nt=0; nt<4; ++nt){
        int n = n0 + wn*64 + nt*16 + l16;
        U1[(size_t)m*EE + n] = __float2bfloat16(tanhf(acc[mt][nt][r] + q1r[n]));
      }
    }
  }
}

// ---------------- init attention/key logits to their scalar biases ----------------
__global__ __launch_bounds__(256)
void k_init_logits(float* __restrict__ ulog, float* __restrict__ uklog,
                   const float* __restrict__ ab3, const float* __restrict__ kb3){
  int i = blockIdx.x*256 + threadIdx.x;
  if (i < BB*LL)  ulog[i]  = ab3[0];
  if (i < BB*KVN) uklog[i] = kb3[0];
}

// ---------------- softmax over L=512, in place ----------------
__global__ __launch_bounds__(256)
void k_softmax(float* __restrict__ ulog){
  __shared__ float sdata[256];
  int b = blockIdx.x, tid = threadIdx.x;
  float* row = ulog + (size_t)b*LL;
  float v0 = row[tid], v1 = row[tid+256];
  sdata[tid] = fmaxf(v0, v1);
  __syncthreads();
  for (int s=128;s>0;s>>=1){ if (tid<s) sdata[tid]=fmaxf(sdata[tid],sdata[tid+s]); __syncthreads(); }
  float mx = sdata[0];
  __syncthreads();
  float e0 = __expf(v0-mx), e1 = __expf(v1-mx);
  sdata[tid] = e0+e1;
  __syncthreads();
  for (int s=128;s>0;s>>=1){ if (tid<s) sdata[tid]+=sdata[tid+s]; __syncthreads(); }
  float inv = 1.f/sdata[0];
  row[tid]     = e0*inv;
  row[tid+256] = e1*inv;
}

// ---------------- h_ctx[b,h] = sum_l a[b,l]*enc[b,l,h] ----------------
__global__ __launch_bounds__(256)
void k_hctx(const float* __restrict__ a, const float* __restrict__ enc,
            float* __restrict__ hctx){
  int hh = blockIdx.x*256 + threadIdx.x;
  int b  = blockIdx.y;
  float s = 0.f;
  for (int l=0;l<LL;l++)
    s += a[(size_t)b*LL + l] * enc[((size_t)b*LL + l)*HH + hh];
  hctx[(size_t)b*HH + hh] = s;
}

// ---------------- hcatb[b][k] = bf16(cat(h_t, h_ctx)) row-major [64][2048] ----------------
__global__ __launch_bounds__(256)
void k_hcat_bf16(const float* __restrict__ ht, const float* __restrict__ hctx,
                 bf16* __restrict__ hcatb){
  int idx = blockIdx.x*256 + threadIdx.x;      // < 64*2048
  int b = idx >> 11, kk = idx & 2047;
  float v = (kk < HH) ? ht[(size_t)b*HH + kk] : hctx[(size_t)b*HH + (kk-HH)];
  hcatb[idx] = __float2bfloat16(v);
}

// ---------------- y init: y[b][v] = alb[v] + (zero-padded uk logits) ----------------
__global__ __launch_bounds__(256)
void k_y_init(const float* __restrict__ alb, const float* __restrict__ uklog,
              float* __restrict__ y){
  int idx = blockIdx.x*256 + threadIdx.x;
  if (idx >= BB*VV) return;
  int b = idx / VV;
  int v = idx - b*VV;
  float o = alb[v];
  int dk = v - (VV - KVN);
  if (dk >= 0) o += uklog[b*KVN + dk];
  y[idx] = o;
}

// =====================================================================
// Final projection MFMA: y[b][v] += (hcatb @ alW[:,v])  (alW fp32->bf16 on the fly)
// BM=64 (all b), BN=128, K-chunk 512 (Ksplit 4), BK=32. grid (393, 4), block 256.
// Each wave: full M=64 x 32 n. atomicAdd into y.
// =====================================================================
__global__ __launch_bounds__(256)
void k_final_mfma(const bf16* __restrict__ hcatb, const float* __restrict__ alW,
                  float* __restrict__ y){
  __shared__ short As[64*40];        // A tile [64 m][32 k] bf16, stride 40
  __shared__ float Bs[32*133];       // B tile [32 k][128 n] fp32, stride 133
  const int tid  = threadIdx.x;
  const int lane = tid & 63, wid = tid >> 6;
  const int quad = lane >> 4, l16 = lane & 15;
  const int n0 = blockIdx.x*128;
  const int kc0 = blockIdx.y*512;

  f32x4 acc[4][2] = {};              // 4 m-frags x 2 n-frags
  for (int k0 = 0; k0 < 512; k0 += 32){
    // stage A: 64x32 bf16 (1 bf16x8 per thread)
    {
      int row = tid >> 2, cg = tid & 3;
      *(bf16x8*)(As + row*40 + cg*8) =
        *(const bf16x8*)((const short*)hcatb + (size_t)row*TWOH + kc0 + k0 + cg*8);
    }
    // stage B: 32x128 fp32 (16 scalar dwords per thread, coalesced)
    #pragma unroll
    for (int i=0;i<16;i++){
      int flat = tid + i*256;
      int kk = flat >> 7, n = flat & 127;
      int gv = n0 + n;
      float v = (gv < VV) ? alW[(size_t)(kc0 + k0 + kk)*VV + gv] : 0.f;
      Bs[kk*133 + n] = v;
    }
    __syncthreads();
    bf16x8 af[4], bfr[2];
    #pragma unroll
    for (int mt=0; mt<4; ++mt)
      af[mt] = *(const bf16x8*)(As + (mt*16 + l16)*40 + quad*8);
    #pragma unroll
    for (int nt=0; nt<2; ++nt){
      int nloc = wid*32 + nt*16 + l16;
      bf16x8 v;
      #pragma unroll
      for (int j=0;j<8;j++)
        v[j] = (short)f2bf(Bs[(quad*8 + j)*133 + nloc]);
      bfr[nt] = v;
    }
    #pragma unroll
    for (int mt=0; mt<4; ++mt)
      #pragma unroll
      for (int nt=0; nt<2; ++nt)
        acc[mt][nt] = __builtin_amdgcn_mfma_f32_16x16x32_bf16(af[mt], bfr[nt], acc[mt][nt], 0, 0, 0);
    __syncthreads();
  }
  #pragma unroll
  for (int nt=0; nt<2; ++nt){
    int v = n0 + wid*32 + nt*16 + l16;
    if (v < VV){
      #pragma unroll
      for (int mt=0; mt<4; ++mt){
        #pragma unroll
        for (int r=0; r<4; ++r){
          int b = mt*16 + quad*4 + r;
          atomicAdd(&y[(size_t)b*VV + v], acc[mt][nt][r]);
        }
      }
    }
  }
}

// ---------------- parallel log-sum-exp: partials over 8 chunks per row ----------------
#define LSE_CH 6283
__global__ __launch_bounds__(256)
void k_lse_part(const float* __restrict__ y, float* __restrict__ pmax,
                float* __restrict__ psum){
  __shared__ float sm[256], ss[256];
  int b = blockIdx.y, chunk = blockIdx.x, tid = threadIdx.x;
  int start = chunk*LSE_CH;
  int end = start + LSE_CH; if (end > VV) end = VV;
  const float* row = y + (size_t)b*VV;
  float m = -1e30f, s = 0.f;
  for (int i = start + tid; i < end; i += 256){
    float v = row[i];
    if (v > m){ s = s*__expf(m - v) + 1.f; m = v; }
    else s += __expf(v - m);
  }
  sm[tid] = m; ss[tid] = s;
  __syncthreads();
  for (int st=128; st>0; st>>=1){
    if (tid < st){
      float m2 = sm[tid+st], s2 = ss[tid+st];
      float M = fmaxf(sm[tid], m2);
      ss[tid] = ss[tid]*__expf(sm[tid]-M) + s2*__expf(m2-M);
      sm[tid] = M;
    }
    __syncthreads();
  }
  if (tid == 0){ pmax[b*8 + chunk] = sm[0]; psum[b*8 + chunk] = ss[0]; }
}

__global__ __launch_bounds__(64)
void k_lse_combine(const float* __restrict__ pmax, const float* __restrict__ psum,
                   float* __restrict__ lse){
  int b = threadIdx.x;
  float m = -1e30f;
  #pragma unroll
  for (int i=0;i<8;i++) m = fmaxf(m, pmax[b*8+i]);
  float s = 0.f;
  #pragma unroll
  for (int i=0;i<8;i++) s += psum[b*8+i]*__expf(pmax[b*8+i]-m);
  lse[b] = m + logf(s);
}

__global__ __launch_bounds__(256)
void k_lse_apply(float* __restrict__ y, const float* __restrict__ lse){
  int idx = blockIdx.x*256 + threadIdx.x;
  if (idx >= BB*VV) return;
  int b = idx / VV;
  y[idx] -= lse[b];
}

extern "C" void kernel_launch(void* const* d_in, const int* in_sizes, int n_in,
                              void* d_out, int out_size, void* d_ws, size_t ws_size,
                              hipStream_t stream) {
  const int*   ids  = (const int*)  d_in[0];
  const float* h    = (const float*)d_in[1];
  const float* c    = (const float*)d_in[2];
  const float* kin  = (const float*)d_in[3];
  const float* ctx  = (const float*)d_in[4];
  const float* enc  = (const float*)d_in[5];
  const float* emb  = (const float*)d_in[6];
  const float* W_ih = (const float*)d_in[7];
  const float* W_hh = (const float*)d_in[8];
  const float* b_ih = (const float*)d_in[9];
  const float* b_hh = (const float*)d_in[10];
  const float* aW1  = (const float*)d_in[11];
  const float* ab1  = (const float*)d_in[12];
  const float* aW2  = (const float*)d_in[13];
  const float* ab2  = (const float*)d_in[14];
  const float* aW3  = (const float*)d_in[15];
  const float* ab3  = (const float*)d_in[16];
  const float* kW1  = (const float*)d_in[17];
  const float* kb1  = (const float*)d_in[18];
  const float* kW2  = (const float*)d_in[19];
  const float* kb2  = (const float*)d_in[20];
  const float* kW3  = (const float*)d_in[21];
  const float* kb3  = (const float*)d_in[22];
  const float* alW  = (const float*)d_in[23];
  const float* alb  = (const float*)d_in[24];

  float* y      = (float*)d_out;
  float* ht_out = y + (size_t)BB*VV;
  float* ct_out = ht_out + (size_t)BB*HH;

  char* w = (char*)d_ws;
  float* gates = (float*)w;  w += (size_t)BB*FH*4;        // 1 MB
  float* q1    = (float*)w;  w += (size_t)BB*EE*4;
  float* p1    = (float*)w;  w += (size_t)BB*EE*4;
  float* p2    = (float*)w;  w += (size_t)KVN*EE*4;       // 2 MB
  float* ulog  = (float*)w;  w += (size_t)BB*LL*4;
  float* uklog = (float*)w;  w += (size_t)BB*KVN*4;
  float* hctx  = (float*)w;  w += (size_t)BB*HH*4;
  bf16*  hcatb = (bf16*)w;   w += (size_t)BB*TWOH*2;      // 256 KB
  bf16*  U1    = (bf16*)w;   w += (size_t)BB*LL*EE*2;     // 33.5 MB
  bf16*  aW1t  = (bf16*)w;   w += (size_t)EE*HH*2;        // 1 MB
  bf16*  aW2t  = (bf16*)w;   w += (size_t)EE*EE*2;        // 0.5 MB
  bf16*  kW2t  = (bf16*)w;   w += (size_t)EE*EE*2;        // 0.5 MB
  float* pmax  = (float*)w;  w += (size_t)BB*8*4;
  float* psum  = (float*)w;  w += (size_t)BB*8*4;
  float* lse   = (float*)w;  w += (size_t)BB*4;

  const int NBLK = (BB*VV + 255)/256;

  // 0. weight transposes -> bf16
  k_transpose_bf16<<<dim3(EE/32, HH/32), 256, 0, stream>>>(aW1, aW1t, HH, EE);
  k_transpose_bf16<<<dim3(EE/32, EE/32), 256, 0, stream>>>(aW2, aW2t, EE, EE);
  k_transpose_bf16<<<dim3(EE/32, EE/32), 256, 0, stream>>>(kW2, kW2t, EE, EE);

  // 1. LSTM front-end (K-split tiled GEMM + atomics into bias-initialized gates)
  k_gates_init<<<(BB*FH)/256, 256, 0, stream>>>(b_ih, b_hh, gates);
  k_embed_gates<<<dim3(FH/64, (EE+HH)/64), 256, 0, stream>>>(ids, h, emb, W_ih, W_hh, gates);
  k_lstm<<<(BB*HH)/256, 256, 0, stream>>>(gates, c, ht_out, ct_out);

  // 2. logits init (bias of third MLP layers)
  k_init_logits<<<(BB*KVN)/256 + 1, 256, 0, stream>>>(ulog, uklog, ab3, kb3);

  // 3. small precomputes
  k_q1p1<<<dim3(EE/256, BB), 256, 0, stream>>>(ht_out, ctx, aW1, ab1, kW1, kb1, q1, p1);
  k_p2<<<dim3(EE/256, KVN), 256, 0, stream>>>(kin, kW1, p2);

  // 4. key-attention path: fully fused (tanh(p1+p2) staged on the fly)
  k_mfma_key<<<dim3(4, (BB*KVN)/128), 256, 0, stream>>>(p1, p2, kW2t, kb2, kW3, uklog);

  // 5. additive attention path
  k_mfma_a1<<<dim3(4, (BB*LL)/128), 256, 0, stream>>>(enc, aW1t, q1, U1);
  k_mfma_tanh_dot<<<dim3(4, (BB*LL)/128), 256, 0, stream>>>(U1, aW2t, ab2, aW3, ulog);
  k_softmax<<<BB, 256, 0, stream>>>(ulog);
  k_hctx<<<dim3(HH/256, BB), 256, 0, stream>>>(ulog, enc, hctx);

  // 6. output projection (streaming MFMA with on-the-fly bf16 of alW) + log_softmax
  k_hcat_bf16<<<(BB*TWOH)/256, 256, 0, stream>>>(ht_out, hctx, hcatb);
  k_y_init<<<NBLK, 256, 0, stream>>>(alb, uklog, y);
  k_final_mfma<<<dim3((VV+127)/128, 4), 256, 0, stream>>>(hcatb, alW, y);
  k_lse_part<<<dim3(8, BB), 256, 0, stream>>>(y, pmax, psum);
  k_lse_combine<<<1, 64, 0, stream>>>(pmax, psum, lse);
  k_lse_apply<<<NBLK, 256, 0, stream>>>(y, lse);
}